// Round 11
// baseline (3510.804 us; speedup 1.0000x reference)
//
#include <hip/hip_runtime.h>
#include <hip/hip_bf16.h>
#include <math.h>

#define T_DIM 128
#define B_DIM 256
#define H_DIM 1024
#define N3    3072
#define KC    3072   // combined K for gates GEMM: 2048 (e) + 1024 (h)
#define KTC   96     // KC/32
#define KTP   32     // H_DIM/32

typedef __attribute__((ext_vector_type(8))) short short8;
typedef __attribute__((ext_vector_type(4))) float float4v;
typedef __attribute__((ext_vector_type(4))) unsigned short ushort4v;

__device__ __forceinline__ unsigned short f2bf(float f) {
  union { float f; unsigned u; } v; v.f = f;
  unsigned u = v.u;
  unsigned r = u + 0x7FFFu + ((u >> 16) & 1u);
  return (unsigned short)(r >> 16);
}

// A-fragment offset for MFMA 16x16x32: lane l holds A[m=16mt+(l&15)][k=32kt+(l>>4)*8+i]
// stored at ((mt*KT + kt)*64 + l)*8 + i
__device__ __forceinline__ size_t afrag(int m, int k, int KT) {
  return ((((size_t)(m >> 4) * KT) + (k >> 5)) * 64
          + ((((k >> 3) & 3) << 4) | (m & 15))) * 8 + (k & 7);
}

__device__ __forceinline__ void store_bf4(unsigned short* p, const float* v) {
  ushort4v u;
  u.x = f2bf(v[0]); u.y = f2bf(v[1]); u.z = f2bf(v[2]); u.w = f2bf(v[3]);
  *(ushort4v*)p = u;
}

__device__ __forceinline__ float sigm(float x) { return 1.f / (1.f + __expf(-x)); }

// IC-coherent 16B load (two relaxed agent-scope u64 atomics) — for hn, which is
// produced by other blocks within the same kernel (r7-validated scheme).
__device__ __forceinline__ short8 cload8(const short8* p) {
  unsigned long long* q = (unsigned long long*)p;
  unsigned long long lo = __hip_atomic_load(q,     __ATOMIC_RELAXED, __HIP_MEMORY_SCOPE_AGENT);
  unsigned long long hi = __hip_atomic_load(q + 1, __ATOMIC_RELAXED, __HIP_MEMORY_SCOPE_AGENT);
  union { unsigned long long u[2]; short8 s; } v;
  v.u[0] = lo; v.u[1] = hi;
  return v.s;
}

// ---------------- resets dtype detection + decode ----------------
__global__ void detect_resets(const int* __restrict__ r, int* __restrict__ flag) {
  __shared__ int f;
  if (threadIdx.x == 0) f = 0;
  __syncthreads();
  int loc = 0;
  for (int i = threadIdx.x; i < 8192; i += 256) {
    if ((unsigned)r[i] > 1u) loc = 1;
  }
  if (loc) f = 1;
  __syncthreads();
  if (threadIdx.x == 0) *flag = f;
}

__global__ __launch_bounds__(256) void decode_resets(
    const void* __restrict__ resets, const int* __restrict__ rflag,
    unsigned char* __restrict__ rb) {
  int t = blockIdx.x, b = threadIdx.x;
  int v;
  if (*rflag) v = (int)((const unsigned char*)resets)[t * B_DIM + b];
  else        v = ((const int*)resets)[t * B_DIM + b];
  rb[t * B_DIM + b] = (v != 0) ? 1 : 0;
}

// ---------------- weight conversion ----------------
// Gates weights, virtual N = 64 jt * 4 groups * 16 cols. group g:
//   0 = r, 1 = z (Wi rows k<2048 | Wh rows k>=2048), 2 = n_i (k<2048), 3 = n_h (k>=2048)
__global__ __launch_bounds__(256) void convert_gates(
    const float* __restrict__ Wi, const float* __restrict__ Wh,
    unsigned short* __restrict__ Wg) {
  int nt = blockIdx.x;   // 0..255
  int kt = blockIdx.y;   // 0..95
  int jt = nt >> 2, g = nt & 3;
  size_t base = ((size_t)nt * KTC + kt) * 512;
  for (int e = threadIdx.x; e < 512; e += 256) {
    int i = e & 7, l = (e >> 3) & 63;
    int k = (kt << 5) + ((l >> 4) << 3) + i;
    int j = (jt << 4) + (l & 15);
    float v = 0.f;
    if (g == 0) v = (k < 2048) ? Wi[(size_t)k * N3 + j] : Wh[(size_t)(k - 2048) * N3 + j];
    else if (g == 1) v = (k < 2048) ? Wi[(size_t)k * N3 + 1024 + j] : Wh[(size_t)(k - 2048) * N3 + 1024 + j];
    else if (g == 2) { if (k < 2048) v = Wi[(size_t)k * N3 + 2048 + j]; }
    else             { if (k >= 2048) v = Wh[(size_t)(k - 2048) * N3 + 2048 + j]; }
    Wg[base + e] = f2bf(v);
  }
}

__global__ __launch_bounds__(256) void convert_wp(const float* __restrict__ W,
                                                  unsigned short* __restrict__ Wsw) {
  int nt = blockIdx.x;   // 0..63
  int kt = blockIdx.y;   // 0..31
  size_t base = ((size_t)nt * KTP + kt) * 512;
  for (int e = threadIdx.x; e < 512; e += 256) {
    int i = e & 7, l = (e >> 3) & 63;
    int k = (kt << 5) + ((l >> 4) << 3) + i;
    int n = (nt << 4) + (l & 15);
    Wsw[base + e] = f2bf(W[(size_t)k * H_DIM + n]);
  }
}

// ---------------- init (t = 0 state) ----------------
__global__ __launch_bounds__(256) void init_state(
    const float* __restrict__ a_all,
    unsigned short* __restrict__ A0, float* __restrict__ h0,
    float* __restrict__ err_out) {
  int b = blockIdx.x, tid = threadIdx.x;
  int j0 = tid * 4;
  const float* arow = a_all + (size_t)b * H_DIM;
  float pv[4], nv[4], zz[4] = {0.f, 0.f, 0.f, 0.f};
  float s = 0.f;
#pragma unroll
  for (int jj = 0; jj < 4; ++jj) {
    float a = arow[j0 + jj];
    pv[jj] = fmaxf(a, 0.f);
    nv[jj] = fmaxf(-a, 0.f);
    s += pv[jj] + nv[jj];
    h0[(size_t)b * H_DIM + j0 + jj] = 0.f;
  }
  store_bf4(A0 + afrag(b, j0, KTC), pv);
  store_bf4(A0 + afrag(b, 1024 + j0, KTC), nv);
  store_bf4(A0 + afrag(b, 2048 + j0, KTC), zz);
  __shared__ float red[256];
  red[tid] = s;
  __syncthreads();
  for (int st = 128; st > 0; st >>= 1) {
    if (tid < st) red[tid] += red[tid + st];
    __syncthreads();
  }
  if (tid == 0) err_out[b] = red[0] * (1.0f / (float)H_DIM);
}

// ---------------- gates k-loop: 4-deep 1-kt rotating pipeline ----------------
template<int GS>
__device__ __forceinline__ void gates_pipe(
    float4v (&acc)[4][4],
    const short8* __restrict__ ap0, const short8* __restrict__ ap1,
    const short8* __restrict__ ap2, const short8* __restrict__ ap3,
    const short8* __restrict__ bpr, const short8* __restrict__ bpz,
    const short8* __restrict__ bpn, int kbeg, int kend) {
  if (kbeg >= kend) return;
  short8 A[4][4];          // [buf][mi]
  short8 R[4], Z[4], N[4]; // [buf]
  int n = kend - kbeg;     // multiple of 4

#pragma unroll
  for (int i = 0; i < 3; ++i) {
    size_t o = (size_t)(kbeg + i) * 64;
    A[i][0] = ap0[o]; A[i][1] = ap1[o]; A[i][2] = ap2[o]; A[i][3] = ap3[o];
    R[i] = bpr[o]; Z[i] = bpz[o]; N[i] = bpn[o];
  }

  for (int kb = 0; kb < n; kb += 4) {
#pragma unroll
    for (int j = 0; j < 4; ++j) {
      const int lb = (j + 3) & 3;        // buffer to refill (static)
      if (kb + j + 3 < n) {
        size_t o = (size_t)(kbeg + kb + j + 3) * 64;
        A[lb][0] = ap0[o]; A[lb][1] = ap1[o]; A[lb][2] = ap2[o]; A[lb][3] = ap3[o];
        R[lb] = bpr[o]; Z[lb] = bpz[o]; N[lb] = bpn[o];
      }
#pragma unroll
      for (int mi = 0; mi < 4; ++mi) {
        acc[mi][0]  = __builtin_amdgcn_mfma_f32_16x16x32_bf16(A[j][mi], R[j], acc[mi][0], 0, 0, 0);
        acc[mi][1]  = __builtin_amdgcn_mfma_f32_16x16x32_bf16(A[j][mi], Z[j], acc[mi][1], 0, 0, 0);
        acc[mi][GS] = __builtin_amdgcn_mfma_f32_16x16x32_bf16(A[j][mi], N[j], acc[mi][GS], 0, 0, 0);
      }
    }
  }
}

// ---------------- fused per-step kernel: gates GEMM + GRU, handoff, pred ----------------
// grid 256 (1 block/CU), 512 threads (8 waves). Block b: jt = b&63 (XCD-pinned
// weight slice), rg2 = b>>6 (64 rows, 4 m-tiles). Gates: 8-way k-split pipeline,
// 2-stage LDS reduce, GRU epilogue on waves 0-3; hn stored IC-direct (packed u32
// agent atomics) + vmcnt drain; flags[t][rg2]++. Then all blocks wait for their
// OWN rg2 group (64 blocks) and run pred tile (mt = b>>4, ntq = b&15) — rows are
// within this block's rg2 group; pred work is spread 1 tile/block over all CUs.
__global__ __launch_bounds__(512, 2) void fused_step(
    const unsigned short* __restrict__ A_sw, const unsigned short* __restrict__ Wg,
    const float* __restrict__ b_i, const float* __restrict__ b_hn,
    const float* __restrict__ h_in, float* __restrict__ h_out,
    unsigned short* __restrict__ A_next, unsigned short* __restrict__ hn_sw,
    const unsigned char* __restrict__ rb, float* __restrict__ r_out,
    const unsigned short* __restrict__ Wp, const float* __restrict__ b_p,
    const float* __restrict__ a_all, float* __restrict__ err_out,
    int* __restrict__ flags, int t) {
  int lane = threadIdx.x & 63, wave = threadIdx.x >> 6;
  int b = blockIdx.x;
  int jt = b & 63;
  int rg2 = b >> 6;   // 0..3

  __shared__ float4v red[4][4][2][64];   // 32 KB (reused by pred reduce)
  __shared__ float rsum_red[4][4][4];

  const short8* A8 = (const short8*)A_sw;
  const short8* B8 = (const short8*)Wg;

  float4v acc[4][4];
#pragma unroll
  for (int mi = 0; mi < 4; ++mi)
#pragma unroll
    for (int g = 0; g < 4; ++g) acc[mi][g] = (float4v){0.f, 0.f, 0.f, 0.f};

  const short8* ap0 = A8 + ((size_t)(rg2 * 4 + 0) * KTC) * 64 + lane;
  const short8* ap1 = A8 + ((size_t)(rg2 * 4 + 1) * KTC) * 64 + lane;
  const short8* ap2 = A8 + ((size_t)(rg2 * 4 + 2) * KTC) * 64 + lane;
  const short8* ap3 = A8 + ((size_t)(rg2 * 4 + 3) * KTC) * 64 + lane;
  const short8* bpr = B8 + ((size_t)(jt * 4 + 0) * KTC) * 64 + lane;
  const short8* bpz = B8 + ((size_t)(jt * 4 + 1) * KTC) * 64 + lane;
  const short8* bpi = B8 + ((size_t)(jt * 4 + 2) * KTC) * 64 + lane;
  const short8* bph = B8 + ((size_t)(jt * 4 + 3) * KTC) * 64 + lane;

  int k0 = wave * 12, k1 = k0 + 12;
  int e_end = (k1 < 64) ? k1 : 64;
  int h_st  = (k0 > 64) ? k0 : 64;

  gates_pipe<2>(acc, ap0, ap1, ap2, ap3, bpr, bpz, bpi, k0, e_end);  // e: r,z,n_i
  gates_pipe<3>(acc, ap0, ap1, ap2, ap3, bpr, bpz, bph, h_st, k1);   // h: r,z,n_h

  // stage 1: waves 4-7 -> waves 0-3 (g split in halves to fit 32 KB)
#pragma unroll
  for (int hh = 0; hh < 2; ++hh) {
    if (wave >= 4) {
#pragma unroll
      for (int mi = 0; mi < 4; ++mi) {
        red[wave - 4][mi][0][lane] = acc[mi][2 * hh];
        red[wave - 4][mi][1][lane] = acc[mi][2 * hh + 1];
      }
    }
    __syncthreads();
    if (wave < 4) {
#pragma unroll
      for (int mi = 0; mi < 4; ++mi) {
        acc[mi][2 * hh]     += red[wave][mi][0][lane];
        acc[mi][2 * hh + 1] += red[wave][mi][1][lane];
      }
    }
    __syncthreads();
  }
  // stage 2: all-to-all among waves 0-3; wave w owns m-tile w
  float4v accs[4];
#pragma unroll
  for (int hh = 0; hh < 2; ++hh) {
    if (wave < 4) {
#pragma unroll
      for (int mi = 0; mi < 4; ++mi) {
        red[wave][mi][0][lane] = acc[mi][2 * hh];
        red[wave][mi][1][lane] = acc[mi][2 * hh + 1];
      }
    }
    __syncthreads();
    if (wave < 4) {
      float4v s0 = red[0][wave][0][lane];
      float4v s1 = red[0][wave][1][lane];
#pragma unroll
      for (int w = 1; w < 4; ++w) {
        s0 += red[w][wave][0][lane];
        s1 += red[w][wave][1][lane];
      }
      accs[2 * hh] = s0; accs[2 * hh + 1] = s1;
    }
    __syncthreads();
  }

  int cl = lane & 15, q = lane >> 4;

  // GRU epilogue (waves 0-3, 16 rows x 16 cols each)
  if (wave < 4) {
    int jcol = (jt << 4) + cl;
    float br_ = b_i[jcol], bz_ = b_i[1024 + jcol], bn_ = b_i[2048 + jcol];
    float bh = b_hn[jcol];
    int row_base = rg2 * 64 + wave * 16 + q * 4;
#pragma unroll
    for (int rr = 0; rr < 4; ++rr) {
      int row = row_base + rr;
      float r = sigm(accs[0][rr] + br_);
      float z = sigm(accs[1][rr] + bz_);
      float n = tanhf(accs[2][rr] + bn_ + r * (accs[3][rr] + bh));
      float hv = h_in[(size_t)row * H_DIM + jcol];
      float nh = (1.f - z) * n + z * hv;
      r_out[((size_t)t * B_DIM + row) * H_DIM + jcol] = nh;
      if (t < T_DIM - 1) {
        // hn: pack bf16 pair across (cl, cl^1), store IC-direct (agent atomic)
        float nh_p = __shfl_xor(nh, 1);
        if ((cl & 1) == 0) {
          unsigned pk = (unsigned)f2bf(nh) | ((unsigned)f2bf(nh_p) << 16);
          __hip_atomic_store((unsigned*)hn_sw + (afrag(row, jcol, KTP) >> 1), pk,
                             __ATOMIC_RELAXED, __HIP_MEMORY_SCOPE_AGENT);
        }
        int rst = rb[(t + 1) * B_DIM + row];
        float hm = rst ? 0.f : nh;
        h_out[(size_t)row * H_DIM + jcol] = hm;
        A_next[afrag(row, 2048 + jcol, KTC)] = f2bf(hm);
      }
    }
    if (t < T_DIM - 1)
      asm volatile("s_waitcnt vmcnt(0)" ::: "memory");   // drain hn stores
  }
  __syncthreads();

  if (t >= T_DIM - 1) return;

  // -------- handoff: wait for own rg2 group's 64 gates blocks --------
  if (threadIdx.x == 0) {
    __hip_atomic_fetch_add(&flags[t * 8 + rg2], 1, __ATOMIC_RELAXED,
                           __HIP_MEMORY_SCOPE_AGENT);
    while (__hip_atomic_load(&flags[t * 8 + rg2], __ATOMIC_RELAXED,
                             __HIP_MEMORY_SCOPE_AGENT) != 64)
      __builtin_amdgcn_s_sleep(1);
  }
  __syncthreads();
  asm volatile("" ::: "memory");

  // -------- pred phase: tile mt = b>>4 (16 rows, within own rg2), ntq = b&15 --------
  int mt = b >> 4, ntq = b & 15;

  const short8* H8 = (const short8*)hn_sw;
  const short8* P8 = (const short8*)Wp;
  const short8* hap = H8 + ((size_t)mt * KTP) * 64 + lane;
  const short8* pb0 = P8 + ((size_t)(ntq * 4 + 0) * KTP) * 64 + lane;
  const short8* pb1 = P8 + ((size_t)(ntq * 4 + 1) * KTP) * 64 + lane;
  const short8* pb2 = P8 + ((size_t)(ntq * 4 + 2) * KTP) * 64 + lane;
  const short8* pb3 = P8 + ((size_t)(ntq * 4 + 3) * KTP) * 64 + lane;

  float4v pacc[4];
#pragma unroll
  for (int n = 0; n < 4; ++n) pacc[n] = (float4v){0.f, 0.f, 0.f, 0.f};

  {
    int pk0 = wave * 4;   // 8 waves x 4 kt = 32 kt
    short8 Aa[4], B0a[4], B1a[4], B2a[4], B3a[4];
#pragma unroll
    for (int kk = 0; kk < 4; ++kk) {
      size_t o = (size_t)(pk0 + kk) * 64;
      Aa[kk] = cload8(&hap[o]);
      B0a[kk] = pb0[o]; B1a[kk] = pb1[o]; B2a[kk] = pb2[o]; B3a[kk] = pb3[o];
    }
#pragma unroll
    for (int kk = 0; kk < 4; ++kk) {
      pacc[0] = __builtin_amdgcn_mfma_f32_16x16x32_bf16(Aa[kk], B0a[kk], pacc[0], 0, 0, 0);
      pacc[1] = __builtin_amdgcn_mfma_f32_16x16x32_bf16(Aa[kk], B1a[kk], pacc[1], 0, 0, 0);
      pacc[2] = __builtin_amdgcn_mfma_f32_16x16x32_bf16(Aa[kk], B2a[kk], pacc[2], 0, 0, 0);
      pacc[3] = __builtin_amdgcn_mfma_f32_16x16x32_bf16(Aa[kk], B3a[kk], pacc[3], 0, 0, 0);
    }
  }

  // reduce across 8 waves (reuse gates red LDS as [8][4][64])
  float4v (*pred_red)[4][64] = (float4v (*)[4][64])red;
#pragma unroll
  for (int n = 0; n < 4; ++n) pred_red[wave][n][lane] = pacc[n];
  __syncthreads();

  if (wave < 4) {
    float4v s = pred_red[0][wave][lane];
#pragma unroll
    for (int w = 1; w < 8; ++w) s += pred_red[w][wave][lane];

    int coln = (ntq * 4 + wave) * 16 + cl;
    float bp = b_p[coln];
    float rsum[4];
#pragma unroll
    for (int rr = 0; rr < 4; ++rr) {
      int row = mt * 16 + q * 4 + rr;
      float ah = fmaxf(s[rr] + bp, 0.f);
      int rst = rb[(t + 1) * B_DIM + row];
      float am = rst ? 0.f : ah;
      float av = a_all[((size_t)(t + 1) * B_DIM + row) * H_DIM + coln];
      float d = av - am;
      float pos = fmaxf(d, 0.f), neg = fmaxf(-d, 0.f);
      A_next[afrag(row, coln, KTC)] = f2bf(pos);
      A_next[afrag(row, 1024 + coln, KTC)] = f2bf(neg);
      rsum[rr] = pos + neg;
    }
#pragma unroll
    for (int rr = 0; rr < 4; ++rr) {
      float sv = rsum[rr];
      sv += __shfl_xor(sv, 1);
      sv += __shfl_xor(sv, 2);
      sv += __shfl_xor(sv, 4);
      sv += __shfl_xor(sv, 8);
      if (cl == 0) rsum_red[wave][q][rr] = sv;
    }
  }
  __syncthreads();
  if (wave == 0 && lane < 16) {
    int qq = lane >> 2, rr = lane & 3;
    float sv = rsum_red[0][qq][rr] + rsum_red[1][qq][rr]
             + rsum_red[2][qq][rr] + rsum_red[3][qq][rr];
    int row = mt * 16 + qq * 4 + rr;
    atomicAdd(err_out + (size_t)(t + 1) * B_DIM + row, sv * (1.0f / (float)H_DIM));
  }
}

// ---------------- launch ----------------
extern "C" void kernel_launch(void* const* d_in, const int* in_sizes, int n_in,
                              void* d_out, int out_size, void* d_ws, size_t ws_size,
                              hipStream_t stream) {
  (void)in_sizes; (void)n_in; (void)out_size; (void)ws_size;
  const float* a_all = (const float*)d_in[0];
  const void*  resets = d_in[1];
  const float* W_i  = (const float*)d_in[2];
  const float* b_i  = (const float*)d_in[3];
  const float* W_h  = (const float*)d_in[4];
  const float* b_hn = (const float*)d_in[5];
  const float* W_p  = (const float*)d_in[6];
  const float* b_p  = (const float*)d_in[7];

  float* r_out = (float*)d_out;
  float* err_out = r_out + (size_t)T_DIM * B_DIM * H_DIM;

  char* ws = (char*)d_ws;
  unsigned short* Wg_sw = (unsigned short*)ws; ws += (size_t)256 * 16 * KC * 2;     // 25.2 MB
  unsigned short* Wp_sw = (unsigned short*)ws; ws += (size_t)H_DIM * H_DIM * 2;     // 2 MB
  unsigned short* A0    = (unsigned short*)ws; ws += (size_t)B_DIM * KC * 2;        // 1.5 MB
  unsigned short* A1    = (unsigned short*)ws; ws += (size_t)B_DIM * KC * 2;        // 1.5 MB
  unsigned short* hn_sw = (unsigned short*)ws; ws += (size_t)B_DIM * H_DIM * 2;     // 0.5 MB
  float* h0 = (float*)ws; ws += (size_t)B_DIM * H_DIM * 4;                          // 1 MB
  float* h1 = (float*)ws; ws += (size_t)B_DIM * H_DIM * 4;                          // 1 MB
  unsigned char* rb = (unsigned char*)ws; ws += T_DIM * B_DIM;                      // 32 KB
  int* rflag = (int*)ws; ws += 256;
  int* flags = (int*)ws; ws += T_DIM * 8 * sizeof(int);                             // 4 KB

  hipMemsetAsync(err_out, 0, (size_t)T_DIM * B_DIM * sizeof(float), stream);
  hipMemsetAsync(flags, 0, T_DIM * 8 * sizeof(int), stream);   // re-zeroed per replay
  detect_resets<<<1, 256, 0, stream>>>((const int*)resets, rflag);
  decode_resets<<<T_DIM, 256, 0, stream>>>(resets, rflag, rb);
  convert_gates<<<dim3(256, KTC), 256, 0, stream>>>(W_i, W_h, Wg_sw);
  convert_wp<<<dim3(H_DIM / 16, KTP), 256, 0, stream>>>(W_p, Wp_sw);
  init_state<<<B_DIM, 256, 0, stream>>>(a_all, A0, h0, err_out);

  for (int t = 0; t < T_DIM; ++t) {
    const unsigned short* Acur = (t & 1) ? A1 : A0;
    unsigned short* Anext      = (t & 1) ? A0 : A1;
    const float* hcur = (t & 1) ? h1 : h0;
    float* hnext      = (t & 1) ? h0 : h1;
    fused_step<<<256, 512, 0, stream>>>(
        Acur, Wg_sw, b_i, b_hn, hcur, hnext, Anext, hn_sw, rb, r_out,
        Wp_sw, b_p, a_all, err_out, flags, t);
  }
}

// Round 12
// 3135.436 us; speedup vs baseline: 1.1197x; 1.1197x over previous
//
#include <hip/hip_runtime.h>
#include <hip/hip_bf16.h>
#include <math.h>

#define T_DIM 128
#define B_DIM 256
#define H_DIM 1024
#define N3    3072
#define KC    3072   // combined K for gates GEMM: 2048 (e) + 1024 (h)
#define KTC   96     // KC/32
#define KTP   32     // H_DIM/32

typedef __attribute__((ext_vector_type(8))) short short8;
typedef __attribute__((ext_vector_type(4))) float float4v;
typedef __attribute__((ext_vector_type(4))) unsigned short ushort4v;

__device__ __forceinline__ unsigned short f2bf(float f) {
  union { float f; unsigned u; } v; v.f = f;
  unsigned u = v.u;
  unsigned r = u + 0x7FFFu + ((u >> 16) & 1u);
  return (unsigned short)(r >> 16);
}

// A-fragment offset for MFMA 16x16x32: lane l holds A[m=16mt+(l&15)][k=32kt+(l>>4)*8+i]
// stored at ((mt*KT + kt)*64 + l)*8 + i
__device__ __forceinline__ size_t afrag(int m, int k, int KT) {
  return ((((size_t)(m >> 4) * KT) + (k >> 5)) * 64
          + ((((k >> 3) & 3) << 4) | (m & 15))) * 8 + (k & 7);
}

__device__ __forceinline__ void store_bf4(unsigned short* p, const float* v) {
  ushort4v u;
  u.x = f2bf(v[0]); u.y = f2bf(v[1]); u.z = f2bf(v[2]); u.w = f2bf(v[3]);
  *(ushort4v*)p = u;
}

__device__ __forceinline__ float sigm(float x) { return 1.f / (1.f + __expf(-x)); }

// flags layout: per (t, rg2): 8 XCD sub-counters + 1 master, 64B apart
#define FLG(t, rg2, x) ((((t) * 4 + (rg2)) * 9 + (x)) * 16)
#define FLAGS_INTS (T_DIM * 4 * 9 * 16)

// ---------------- resets dtype detection + decode ----------------
__global__ void detect_resets(const int* __restrict__ r, int* __restrict__ flag) {
  __shared__ int f;
  if (threadIdx.x == 0) f = 0;
  __syncthreads();
  int loc = 0;
  for (int i = threadIdx.x; i < 8192; i += 256) {
    if ((unsigned)r[i] > 1u) loc = 1;
  }
  if (loc) f = 1;
  __syncthreads();
  if (threadIdx.x == 0) *flag = f;
}

__global__ __launch_bounds__(256) void decode_resets(
    const void* __restrict__ resets, const int* __restrict__ rflag,
    unsigned char* __restrict__ rb) {
  int t = blockIdx.x, b = threadIdx.x;
  int v;
  if (*rflag) v = (int)((const unsigned char*)resets)[t * B_DIM + b];
  else        v = ((const int*)resets)[t * B_DIM + b];
  rb[t * B_DIM + b] = (v != 0) ? 1 : 0;
}

// ---------------- weight conversion ----------------
// Gates weights, virtual N = 64 jt * 4 groups * 16 cols. group g:
//   0 = r, 1 = z (Wi rows k<2048 | Wh rows k>=2048), 2 = n_i (k<2048), 3 = n_h (k>=2048)
__global__ __launch_bounds__(256) void convert_gates(
    const float* __restrict__ Wi, const float* __restrict__ Wh,
    unsigned short* __restrict__ Wg) {
  int nt = blockIdx.x;   // 0..255
  int kt = blockIdx.y;   // 0..95
  int jt = nt >> 2, g = nt & 3;
  size_t base = ((size_t)nt * KTC + kt) * 512;
  for (int e = threadIdx.x; e < 512; e += 256) {
    int i = e & 7, l = (e >> 3) & 63;
    int k = (kt << 5) + ((l >> 4) << 3) + i;
    int j = (jt << 4) + (l & 15);
    float v = 0.f;
    if (g == 0) v = (k < 2048) ? Wi[(size_t)k * N3 + j] : Wh[(size_t)(k - 2048) * N3 + j];
    else if (g == 1) v = (k < 2048) ? Wi[(size_t)k * N3 + 1024 + j] : Wh[(size_t)(k - 2048) * N3 + 1024 + j];
    else if (g == 2) { if (k < 2048) v = Wi[(size_t)k * N3 + 2048 + j]; }
    else             { if (k >= 2048) v = Wh[(size_t)(k - 2048) * N3 + 2048 + j]; }
    Wg[base + e] = f2bf(v);
  }
}

__global__ __launch_bounds__(256) void convert_wp(const float* __restrict__ W,
                                                  unsigned short* __restrict__ Wsw) {
  int nt = blockIdx.x;   // 0..63
  int kt = blockIdx.y;   // 0..31
  size_t base = ((size_t)nt * KTP + kt) * 512;
  for (int e = threadIdx.x; e < 512; e += 256) {
    int i = e & 7, l = (e >> 3) & 63;
    int k = (kt << 5) + ((l >> 4) << 3) + i;
    int n = (nt << 4) + (l & 15);
    Wsw[base + e] = f2bf(W[(size_t)k * H_DIM + n]);
  }
}

// ---------------- init (t = 0 state) ----------------
__global__ __launch_bounds__(256) void init_state(
    const float* __restrict__ a_all,
    unsigned short* __restrict__ A0, float* __restrict__ h0,
    float* __restrict__ err_out) {
  int b = blockIdx.x, tid = threadIdx.x;
  int j0 = tid * 4;
  const float* arow = a_all + (size_t)b * H_DIM;
  float pv[4], nv[4], zz[4] = {0.f, 0.f, 0.f, 0.f};
  float s = 0.f;
#pragma unroll
  for (int jj = 0; jj < 4; ++jj) {
    float a = arow[j0 + jj];
    pv[jj] = fmaxf(a, 0.f);
    nv[jj] = fmaxf(-a, 0.f);
    s += pv[jj] + nv[jj];
    h0[(size_t)b * H_DIM + j0 + jj] = 0.f;
  }
  store_bf4(A0 + afrag(b, j0, KTC), pv);
  store_bf4(A0 + afrag(b, 1024 + j0, KTC), nv);
  store_bf4(A0 + afrag(b, 2048 + j0, KTC), zz);
  __shared__ float red[256];
  red[tid] = s;
  __syncthreads();
  for (int st = 128; st > 0; st >>= 1) {
    if (tid < st) red[tid] += red[tid + st];
    __syncthreads();
  }
  if (tid == 0) err_out[b] = red[0] * (1.0f / (float)H_DIM);
}

// ---------------- gates GEMM helpers: 4 m-tiles, reg-staged 2-kt chunks (r8-proven) ----------------
__device__ __forceinline__ void load_chunk4(
    const short8* __restrict__ ap0, const short8* __restrict__ ap1,
    const short8* __restrict__ ap2, const short8* __restrict__ ap3,
    const short8* __restrict__ bpr, const short8* __restrict__ bpz,
    const short8* __restrict__ bpn, int kb,
    short8 (&A)[4][2], short8 (&R)[2], short8 (&Z)[2], short8 (&N)[2]) {
#pragma unroll
  for (int kk = 0; kk < 2; ++kk) {
    size_t o = (size_t)(kb + kk) * 64;
    A[0][kk] = ap0[o]; A[1][kk] = ap1[o]; A[2][kk] = ap2[o]; A[3][kk] = ap3[o];
    R[kk] = bpr[o]; Z[kk] = bpz[o]; N[kk] = bpn[o];
  }
}

template<int GS>
__device__ __forceinline__ void mfma_chunk4(
    float4v (&acc)[4][4],
    const short8 (&A)[4][2], const short8 (&R)[2], const short8 (&Z)[2],
    const short8 (&N)[2]) {
#pragma unroll
  for (int kk = 0; kk < 2; ++kk) {
#pragma unroll
    for (int mi = 0; mi < 4; ++mi) {
      acc[mi][0]  = __builtin_amdgcn_mfma_f32_16x16x32_bf16(A[mi][kk], R[kk], acc[mi][0], 0, 0, 0);
      acc[mi][1]  = __builtin_amdgcn_mfma_f32_16x16x32_bf16(A[mi][kk], Z[kk], acc[mi][1], 0, 0, 0);
      acc[mi][GS] = __builtin_amdgcn_mfma_f32_16x16x32_bf16(A[mi][kk], N[kk], acc[mi][GS], 0, 0, 0);
    }
  }
}

// segment length must be a multiple of 4 kt (here 4 or 8)
template<int GS>
__device__ __forceinline__ void gates_seg4(
    float4v (&acc)[4][4],
    const short8* __restrict__ ap0, const short8* __restrict__ ap1,
    const short8* __restrict__ ap2, const short8* __restrict__ ap3,
    const short8* __restrict__ bpr, const short8* __restrict__ bpz,
    const short8* __restrict__ bpn, int kbeg, int kend) {
  if (kbeg >= kend) return;
  short8 Aa[4][2], Ra[2], Za[2], Na[2];
  short8 Ab[4][2], Rb[2], Zb[2], Nb[2];
  load_chunk4(ap0, ap1, ap2, ap3, bpr, bpz, bpn, kbeg, Aa, Ra, Za, Na);
  for (int kb = kbeg; kb < kend; kb += 4) {
    load_chunk4(ap0, ap1, ap2, ap3, bpr, bpz, bpn, kb + 2, Ab, Rb, Zb, Nb);
    mfma_chunk4<GS>(acc, Aa, Ra, Za, Na);
    if (kb + 4 < kend)
      load_chunk4(ap0, ap1, ap2, ap3, bpr, bpz, bpn, kb + 4, Aa, Ra, Za, Na);
    mfma_chunk4<GS>(acc, Ab, Rb, Zb, Nb);
  }
}

// ---------------- fused step kernel: pred(t-1) -> gates(t) ----------------
// grid 256 (1 block/CU), 512 threads (8 waves). Block b: jt=b&63 (XCD-pinned
// weight slice), rg2=b>>6 (64 rows); pred tile mt=b>>4, ntq=b&15 (mt>>2 == rg2).
// Order: [pred(t-1): normal loads of hn/Wp/a; agent-atomic A_cur e-writes; drain;
// hierarchical flag bump] -> [gates h-segment kt64..95 (prev-dispatch data)] ->
// [flag wait (hidden behind h-segment)] -> [gates e-segment kt0..63: lines
// first-touched after flag -> fetched from IC, fresh] -> [reduce + GRU epilogue].
__global__ __launch_bounds__(512, 2) void step_fused(
    unsigned short* __restrict__ A_cur, const unsigned short* __restrict__ Wg,
    const float* __restrict__ b_i, const float* __restrict__ b_hn,
    const float* __restrict__ h_in, float* __restrict__ h_out,
    unsigned short* __restrict__ A_next, unsigned short* __restrict__ hn_sw,
    const unsigned char* __restrict__ rb, float* __restrict__ r_out,
    const unsigned short* __restrict__ Wp, const float* __restrict__ b_p,
    const float* __restrict__ a_all, float* __restrict__ err_out,
    int* __restrict__ flags, int t) {
  int lane = threadIdx.x & 63, wave = threadIdx.x >> 6;
  int b = blockIdx.x;
  int jt = b & 63;
  int rg2 = b >> 6;   // 0..3

  __shared__ float4v red[4][4][2][64];   // 32 KB (pred reduce overlays this)
  __shared__ float rsum_red[4][4][4];

  int cl = lane & 15, q = lane >> 4;

  // ======== phase 0: pred for step t-1 (skip at t==0) ========
  if (t > 0) {
    int ntq = b & 15, mt = b >> 4;
    const short8* H8 = (const short8*)hn_sw;
    const short8* P8 = (const short8*)Wp;
    const short8* hap = H8 + ((size_t)mt * KTP) * 64 + lane;
    const short8* pb0 = P8 + ((size_t)(ntq * 4 + 0) * KTP) * 64 + lane;
    const short8* pb1 = P8 + ((size_t)(ntq * 4 + 1) * KTP) * 64 + lane;
    const short8* pb2 = P8 + ((size_t)(ntq * 4 + 2) * KTP) * 64 + lane;
    const short8* pb3 = P8 + ((size_t)(ntq * 4 + 3) * KTP) * 64 + lane;

    float4v pacc[4];
#pragma unroll
    for (int n = 0; n < 4; ++n) pacc[n] = (float4v){0.f, 0.f, 0.f, 0.f};

    {
      int pk0 = wave * 4;   // 8 waves x 4 kt = 32 kt
      short8 Aa[4], B0a[4], B1a[4], B2a[4], B3a[4];
#pragma unroll
      for (int kk = 0; kk < 4; ++kk) {
        size_t o = (size_t)(pk0 + kk) * 64;
        Aa[kk] = hap[o];
        B0a[kk] = pb0[o]; B1a[kk] = pb1[o]; B2a[kk] = pb2[o]; B3a[kk] = pb3[o];
      }
#pragma unroll
      for (int kk = 0; kk < 4; ++kk) {
        pacc[0] = __builtin_amdgcn_mfma_f32_16x16x32_bf16(Aa[kk], B0a[kk], pacc[0], 0, 0, 0);
        pacc[1] = __builtin_amdgcn_mfma_f32_16x16x32_bf16(Aa[kk], B1a[kk], pacc[1], 0, 0, 0);
        pacc[2] = __builtin_amdgcn_mfma_f32_16x16x32_bf16(Aa[kk], B2a[kk], pacc[2], 0, 0, 0);
        pacc[3] = __builtin_amdgcn_mfma_f32_16x16x32_bf16(Aa[kk], B3a[kk], pacc[3], 0, 0, 0);
      }
    }

    float4v (*pred_red)[4][64] = (float4v (*)[4][64])red;
#pragma unroll
    for (int n = 0; n < 4; ++n) pred_red[wave][n][lane] = pacc[n];
    __syncthreads();

    if (wave < 4) {
      float4v s = pred_red[0][wave][lane];
#pragma unroll
      for (int w = 1; w < 8; ++w) s += pred_red[w][wave][lane];

      int coln = (ntq * 4 + wave) * 16 + cl;
      float bp = b_p[coln];
      float rsum[4];
#pragma unroll
      for (int rr = 0; rr < 4; ++rr) {
        int row = mt * 16 + q * 4 + rr;
        float ah = fmaxf(s[rr] + bp, 0.f);
        int rst = rb[t * B_DIM + row];        // reset at step t zeroes ahat
        float am = rst ? 0.f : ah;
        float av = a_all[((size_t)t * B_DIM + row) * H_DIM + coln];
        float d = av - am;
        float pos = fmaxf(d, 0.f), neg = fmaxf(-d, 0.f);
        // pack bf16 pairs across (cl, cl^1); IC-direct agent atomic stores
        float pos_p = __shfl_xor(pos, 1);
        float neg_p = __shfl_xor(neg, 1);
        if ((cl & 1) == 0) {
          unsigned pk = (unsigned)f2bf(pos) | ((unsigned)f2bf(pos_p) << 16);
          __hip_atomic_store((unsigned*)A_cur + (afrag(row, coln, KTC) >> 1), pk,
                             __ATOMIC_RELAXED, __HIP_MEMORY_SCOPE_AGENT);
          unsigned nk = (unsigned)f2bf(neg) | ((unsigned)f2bf(neg_p) << 16);
          __hip_atomic_store((unsigned*)A_cur + (afrag(row, 1024 + coln, KTC) >> 1), nk,
                             __ATOMIC_RELAXED, __HIP_MEMORY_SCOPE_AGENT);
        }
        rsum[rr] = pos + neg;
      }
      asm volatile("s_waitcnt vmcnt(0)" ::: "memory");   // drain e-part stores
#pragma unroll
      for (int rr = 0; rr < 4; ++rr) {
        float sv = rsum[rr];
        sv += __shfl_xor(sv, 1);
        sv += __shfl_xor(sv, 2);
        sv += __shfl_xor(sv, 4);
        sv += __shfl_xor(sv, 8);
        if (cl == 0) rsum_red[wave][q][rr] = sv;
      }
    }
    __syncthreads();
    if (wave == 0 && lane < 16) {
      int qq = lane >> 2, rr = lane & 3;
      float sv = rsum_red[0][qq][rr] + rsum_red[1][qq][rr]
               + rsum_red[2][qq][rr] + rsum_red[3][qq][rr];
      int row = (b >> 4) * 16 + qq * 4 + rr;
      atomicAdd(err_out + (size_t)t * B_DIM + row, sv * (1.0f / (float)H_DIM));
    }
    // hierarchical flag bump: 8 blocks per (rg2, xcd) sub-counter, 8 subs -> master
    if (threadIdx.x == 0) {
      int x = b & 7;
      int p = __hip_atomic_fetch_add(&flags[FLG(t, rg2, x)], 1,
                                     __ATOMIC_RELAXED, __HIP_MEMORY_SCOPE_AGENT);
      if (p == 7)
        __hip_atomic_fetch_add(&flags[FLG(t, rg2, 8)], 1,
                               __ATOMIC_RELAXED, __HIP_MEMORY_SCOPE_AGENT);
    }
    __syncthreads();
  }

  // ======== gates GEMM for step t ========
  const short8* A8 = (const short8*)A_cur;
  const short8* B8 = (const short8*)Wg;

  float4v acc[4][4];
#pragma unroll
  for (int mi = 0; mi < 4; ++mi)
#pragma unroll
    for (int g = 0; g < 4; ++g) acc[mi][g] = (float4v){0.f, 0.f, 0.f, 0.f};

  const short8* ap0 = A8 + ((size_t)(rg2 * 4 + 0) * KTC) * 64 + lane;
  const short8* ap1 = A8 + ((size_t)(rg2 * 4 + 1) * KTC) * 64 + lane;
  const short8* ap2 = A8 + ((size_t)(rg2 * 4 + 2) * KTC) * 64 + lane;
  const short8* ap3 = A8 + ((size_t)(rg2 * 4 + 3) * KTC) * 64 + lane;
  const short8* bpr = B8 + ((size_t)(jt * 4 + 0) * KTC) * 64 + lane;
  const short8* bpz = B8 + ((size_t)(jt * 4 + 1) * KTC) * 64 + lane;
  const short8* bpi = B8 + ((size_t)(jt * 4 + 2) * KTC) * 64 + lane;
  const short8* bph = B8 + ((size_t)(jt * 4 + 3) * KTC) * 64 + lane;

  // phase 1: h-segment (kt 64..96, 4 kt/wave) — data from previous dispatch
  gates_seg4<3>(acc, ap0, ap1, ap2, ap3, bpr, bpz, bph,
                64 + wave * 4, 64 + wave * 4 + 4);

  // phase 2: wait for own rg2's 64 pred tiles (usually already done)
  if (t > 0) {
    if (threadIdx.x == 0) {
      while (__hip_atomic_load(&flags[FLG(t, rg2, 8)], __ATOMIC_RELAXED,
                               __HIP_MEMORY_SCOPE_AGENT) != 8)
        __builtin_amdgcn_s_sleep(1);
    }
    __syncthreads();
    asm volatile("" ::: "memory");
  }

  // phase 3: e-segment (kt 0..64, 8 kt/wave) — lines first-touched after flag
  gates_seg4<2>(acc, ap0, ap1, ap2, ap3, bpr, bpz, bpi,
                wave * 8, wave * 8 + 8);

  // stage 1: waves 4-7 -> waves 0-3 (g split in halves to fit 32 KB)
#pragma unroll
  for (int hh = 0; hh < 2; ++hh) {
    if (wave >= 4) {
#pragma unroll
      for (int mi = 0; mi < 4; ++mi) {
        red[wave - 4][mi][0][lane] = acc[mi][2 * hh];
        red[wave - 4][mi][1][lane] = acc[mi][2 * hh + 1];
      }
    }
    __syncthreads();
    if (wave < 4) {
#pragma unroll
      for (int mi = 0; mi < 4; ++mi) {
        acc[mi][2 * hh]     += red[wave][mi][0][lane];
        acc[mi][2 * hh + 1] += red[wave][mi][1][lane];
      }
    }
    __syncthreads();
  }
  // stage 2: all-to-all among waves 0-3; wave w owns m-tile w
  float4v accs[4];
#pragma unroll
  for (int hh = 0; hh < 2; ++hh) {
    if (wave < 4) {
#pragma unroll
      for (int mi = 0; mi < 4; ++mi) {
        red[wave][mi][0][lane] = acc[mi][2 * hh];
        red[wave][mi][1][lane] = acc[mi][2 * hh + 1];
      }
    }
    __syncthreads();
    if (wave < 4) {
      float4v s0 = red[0][wave][0][lane];
      float4v s1 = red[0][wave][1][lane];
#pragma unroll
      for (int w = 1; w < 4; ++w) {
        s0 += red[w][wave][0][lane];
        s1 += red[w][wave][1][lane];
      }
      accs[2 * hh] = s0; accs[2 * hh + 1] = s1;
    }
    __syncthreads();
  }

  // GRU epilogue (waves 0-3, 16 rows x 16 cols each)
  if (wave < 4) {
    int jcol = (jt << 4) + cl;
    float br_ = b_i[jcol], bz_ = b_i[1024 + jcol], bn_ = b_i[2048 + jcol];
    float bh = b_hn[jcol];
    int row_base = rg2 * 64 + wave * 16 + q * 4;
#pragma unroll
    for (int rr = 0; rr < 4; ++rr) {
      int row = row_base + rr;
      float r = sigm(accs[0][rr] + br_);
      float z = sigm(accs[1][rr] + bz_);
      float n = tanhf(accs[2][rr] + bn_ + r * (accs[3][rr] + bh));
      float hv = h_in[(size_t)row * H_DIM + jcol];
      float nh = (1.f - z) * n + z * hv;
      r_out[((size_t)t * B_DIM + row) * H_DIM + jcol] = nh;
      if (t < T_DIM - 1) {
        hn_sw[afrag(row, jcol, KTP)] = f2bf(nh);     // next dispatch's pred reads
        int rst = rb[(t + 1) * B_DIM + row];
        float hm = rst ? 0.f : nh;
        h_out[(size_t)row * H_DIM + jcol] = hm;
        A_next[afrag(row, 2048 + jcol, KTC)] = f2bf(hm);
      }
    }
  }
}

// ---------------- launch ----------------
extern "C" void kernel_launch(void* const* d_in, const int* in_sizes, int n_in,
                              void* d_out, int out_size, void* d_ws, size_t ws_size,
                              hipStream_t stream) {
  (void)in_sizes; (void)n_in; (void)out_size; (void)ws_size;
  const float* a_all = (const float*)d_in[0];
  const void*  resets = d_in[1];
  const float* W_i  = (const float*)d_in[2];
  const float* b_i  = (const float*)d_in[3];
  const float* W_h  = (const float*)d_in[4];
  const float* b_hn = (const float*)d_in[5];
  const float* W_p  = (const float*)d_in[6];
  const float* b_p  = (const float*)d_in[7];

  float* r_out = (float*)d_out;
  float* err_out = r_out + (size_t)T_DIM * B_DIM * H_DIM;

  char* ws = (char*)d_ws;
  unsigned short* Wg_sw = (unsigned short*)ws; ws += (size_t)256 * 16 * KC * 2;     // 25.2 MB
  unsigned short* Wp_sw = (unsigned short*)ws; ws += (size_t)H_DIM * H_DIM * 2;     // 2 MB
  unsigned short* A0    = (unsigned short*)ws; ws += (size_t)B_DIM * KC * 2;        // 1.5 MB
  unsigned short* A1    = (unsigned short*)ws; ws += (size_t)B_DIM * KC * 2;        // 1.5 MB
  unsigned short* hn_sw = (unsigned short*)ws; ws += (size_t)B_DIM * H_DIM * 2;     // 0.5 MB
  float* h0 = (float*)ws; ws += (size_t)B_DIM * H_DIM * 4;                          // 1 MB
  float* h1 = (float*)ws; ws += (size_t)B_DIM * H_DIM * 4;                          // 1 MB
  unsigned char* rb = (unsigned char*)ws; ws += T_DIM * B_DIM;                      // 32 KB
  int* rflag = (int*)ws; ws += 256;
  int* flags = (int*)ws; ws += FLAGS_INTS * sizeof(int);                            // 288 KB

  hipMemsetAsync(err_out, 0, (size_t)T_DIM * B_DIM * sizeof(float), stream);
  hipMemsetAsync(flags, 0, FLAGS_INTS * sizeof(int), stream);   // re-zeroed per replay
  detect_resets<<<1, 256, 0, stream>>>((const int*)resets, rflag);
  decode_resets<<<T_DIM, 256, 0, stream>>>(resets, rflag, rb);
  convert_gates<<<dim3(256, KTC), 256, 0, stream>>>(W_i, W_h, Wg_sw);
  convert_wp<<<dim3(H_DIM / 16, KTP), 256, 0, stream>>>(W_p, Wp_sw);
  init_state<<<B_DIM, 256, 0, stream>>>(a_all, A0, h0, err_out);

  for (int t = 0; t < T_DIM; ++t) {
    unsigned short* Acur  = (t & 1) ? A1 : A0;
    unsigned short* Anext = (t & 1) ? A0 : A1;
    const float* hcur = (t & 1) ? h1 : h0;
    float* hnext      = (t & 1) ? h0 : h1;
    step_fused<<<256, 512, 0, stream>>>(
        Acur, Wg_sw, b_i, b_hn, hcur, hnext, Anext, hn_sw, rb, r_out,
        Wp_sw, b_p, a_all, err_out, flags, t);
  }
}

// Round 13
// 2501.770 us; speedup vs baseline: 1.4033x; 1.2533x over previous
//
#include <hip/hip_runtime.h>
#include <hip/hip_bf16.h>
#include <math.h>

#define T_DIM 128
#define B_DIM 256
#define H_DIM 1024
#define N3    3072
#define KC    3072   // combined K for gates GEMM: 2048 (e) + 1024 (h)
#define KTC   96     // KC/32
#define KTP   32     // H_DIM/32

typedef __attribute__((ext_vector_type(8))) short short8;
typedef __attribute__((ext_vector_type(4))) float float4v;
typedef __attribute__((ext_vector_type(4))) unsigned short ushort4v;

__device__ __forceinline__ unsigned short f2bf(float f) {
  union { float f; unsigned u; } v; v.f = f;
  unsigned u = v.u;
  unsigned r = u + 0x7FFFu + ((u >> 16) & 1u);
  return (unsigned short)(r >> 16);
}

// A-fragment offset for MFMA 16x16x32: lane l holds A[m=16mt+(l&15)][k=32kt+(l>>4)*8+i]
// stored at ((mt*KT + kt)*64 + l)*8 + i
__device__ __forceinline__ size_t afrag(int m, int k, int KT) {
  return ((((size_t)(m >> 4) * KT) + (k >> 5)) * 64
          + ((((k >> 3) & 3) << 4) | (m & 15))) * 8 + (k & 7);
}

__device__ __forceinline__ void store_bf4(unsigned short* p, const float* v) {
  ushort4v u;
  u.x = f2bf(v[0]); u.y = f2bf(v[1]); u.z = f2bf(v[2]); u.w = f2bf(v[3]);
  *(ushort4v*)p = u;
}

__device__ __forceinline__ float sigm(float x) { return 1.f / (1.f + __expf(-x)); }

// ---------------- resets dtype detection + decode ----------------
__global__ void detect_resets(const int* __restrict__ r, int* __restrict__ flag) {
  __shared__ int f;
  if (threadIdx.x == 0) f = 0;
  __syncthreads();
  int loc = 0;
  for (int i = threadIdx.x; i < 8192; i += 256) {
    if ((unsigned)r[i] > 1u) loc = 1;
  }
  if (loc) f = 1;
  __syncthreads();
  if (threadIdx.x == 0) *flag = f;
}

__global__ __launch_bounds__(256) void decode_resets(
    const void* __restrict__ resets, const int* __restrict__ rflag,
    unsigned char* __restrict__ rb) {
  int t = blockIdx.x, b = threadIdx.x;
  int v;
  if (*rflag) v = (int)((const unsigned char*)resets)[t * B_DIM + b];
  else        v = ((const int*)resets)[t * B_DIM + b];
  rb[t * B_DIM + b] = (v != 0) ? 1 : 0;
}

// ---------------- weight conversion ----------------
// Gates weights, virtual N = 64 jt * 4 groups * 16 cols. group g:
//   0 = r, 1 = z (Wi rows k<2048 | Wh rows k>=2048), 2 = n_i (k<2048), 3 = n_h (k>=2048)
__global__ __launch_bounds__(256) void convert_gates(
    const float* __restrict__ Wi, const float* __restrict__ Wh,
    unsigned short* __restrict__ Wg) {
  int nt = blockIdx.x;   // 0..255
  int kt = blockIdx.y;   // 0..95
  int jt = nt >> 2, g = nt & 3;
  size_t base = ((size_t)nt * KTC + kt) * 512;
  for (int e = threadIdx.x; e < 512; e += 256) {
    int i = e & 7, l = (e >> 3) & 63;
    int k = (kt << 5) + ((l >> 4) << 3) + i;
    int j = (jt << 4) + (l & 15);
    float v = 0.f;
    if (g == 0) v = (k < 2048) ? Wi[(size_t)k * N3 + j] : Wh[(size_t)(k - 2048) * N3 + j];
    else if (g == 1) v = (k < 2048) ? Wi[(size_t)k * N3 + 1024 + j] : Wh[(size_t)(k - 2048) * N3 + 1024 + j];
    else if (g == 2) { if (k < 2048) v = Wi[(size_t)k * N3 + 2048 + j]; }
    else             { if (k >= 2048) v = Wh[(size_t)(k - 2048) * N3 + 2048 + j]; }
    Wg[base + e] = f2bf(v);
  }
}

__global__ __launch_bounds__(256) void convert_wp(const float* __restrict__ W,
                                                  unsigned short* __restrict__ Wsw) {
  int nt = blockIdx.x;   // 0..63
  int kt = blockIdx.y;   // 0..31
  size_t base = ((size_t)nt * KTP + kt) * 512;
  for (int e = threadIdx.x; e < 512; e += 256) {
    int i = e & 7, l = (e >> 3) & 63;
    int k = (kt << 5) + ((l >> 4) << 3) + i;
    int n = (nt << 4) + (l & 15);
    Wsw[base + e] = f2bf(W[(size_t)k * H_DIM + n]);
  }
}

// ---------------- init (t = 0 state) ----------------
__global__ __launch_bounds__(256) void init_state(
    const float* __restrict__ a_all,
    unsigned short* __restrict__ A0, float* __restrict__ h0,
    float* __restrict__ err_out) {
  int b = blockIdx.x, tid = threadIdx.x;
  int j0 = tid * 4;
  const float* arow = a_all + (size_t)b * H_DIM;
  float pv[4], nv[4], zz[4] = {0.f, 0.f, 0.f, 0.f};
  float s = 0.f;
#pragma unroll
  for (int jj = 0; jj < 4; ++jj) {
    float a = arow[j0 + jj];
    pv[jj] = fmaxf(a, 0.f);
    nv[jj] = fmaxf(-a, 0.f);
    s += pv[jj] + nv[jj];
    h0[(size_t)b * H_DIM + j0 + jj] = 0.f;
  }
  store_bf4(A0 + afrag(b, j0, KTC), pv);
  store_bf4(A0 + afrag(b, 1024 + j0, KTC), nv);
  store_bf4(A0 + afrag(b, 2048 + j0, KTC), zz);
  __shared__ float red[256];
  red[tid] = s;
  __syncthreads();
  for (int st = 128; st > 0; st >>= 1) {
    if (tid < st) red[tid] += red[tid + st];
    __syncthreads();
  }
  if (tid == 0) err_out[b] = red[0] * (1.0f / (float)H_DIM);
}

// ---------------- gates GEMM helpers: 4 m-tiles, reg-staged 2-kt chunks ----------------
// A loads issue FIRST (IC-class latency), then weights (L2-class).
__device__ __forceinline__ void load_chunk4(
    const short8* __restrict__ ap0, const short8* __restrict__ ap1,
    const short8* __restrict__ ap2, const short8* __restrict__ ap3,
    const short8* __restrict__ bpr, const short8* __restrict__ bpz,
    const short8* __restrict__ bpn, int kb,
    short8 (&A)[4][2], short8 (&R)[2], short8 (&Z)[2], short8 (&N)[2]) {
  size_t o0 = (size_t)kb * 64, o1 = (size_t)(kb + 1) * 64;
  A[0][0] = ap0[o0]; A[1][0] = ap1[o0]; A[2][0] = ap2[o0]; A[3][0] = ap3[o0];
  A[0][1] = ap0[o1]; A[1][1] = ap1[o1]; A[2][1] = ap2[o1]; A[3][1] = ap3[o1];
  R[0] = bpr[o0]; Z[0] = bpz[o0]; N[0] = bpn[o0];
  R[1] = bpr[o1]; Z[1] = bpz[o1]; N[1] = bpn[o1];
}

template<int GS>
__device__ __forceinline__ void mfma_chunk4(
    float4v (&acc)[4][4],
    const short8 (&A)[4][2], const short8 (&R)[2], const short8 (&Z)[2],
    const short8 (&N)[2]) {
#pragma unroll
  for (int kk = 0; kk < 2; ++kk) {
#pragma unroll
    for (int mi = 0; mi < 4; ++mi) {
      acc[mi][0]  = __builtin_amdgcn_mfma_f32_16x16x32_bf16(A[mi][kk], R[kk], acc[mi][0], 0, 0, 0);
      acc[mi][1]  = __builtin_amdgcn_mfma_f32_16x16x32_bf16(A[mi][kk], Z[kk], acc[mi][1], 0, 0, 0);
      acc[mi][GS] = __builtin_amdgcn_mfma_f32_16x16x32_bf16(A[mi][kk], N[kk], acc[mi][GS], 0, 0, 0);
    }
  }
}

// segment lengths here are always multiples of 4 kt (12, 4, 8)
template<int GS>
__device__ __forceinline__ void gates_seg4(
    float4v (&acc)[4][4],
    const short8* __restrict__ ap0, const short8* __restrict__ ap1,
    const short8* __restrict__ ap2, const short8* __restrict__ ap3,
    const short8* __restrict__ bpr, const short8* __restrict__ bpz,
    const short8* __restrict__ bpn, int kbeg, int kend) {
  if (kbeg >= kend) return;
  short8 Aa[4][2], Ra[2], Za[2], Na[2];
  short8 Ab[4][2], Rb[2], Zb[2], Nb[2];
  load_chunk4(ap0, ap1, ap2, ap3, bpr, bpz, bpn, kbeg, Aa, Ra, Za, Na);
  for (int kb = kbeg; kb < kend; kb += 4) {
    load_chunk4(ap0, ap1, ap2, ap3, bpr, bpz, bpn, kb + 2, Ab, Rb, Zb, Nb);
    mfma_chunk4<GS>(acc, Aa, Ra, Za, Na);
    if (kb + 4 < kend)
      load_chunk4(ap0, ap1, ap2, ap3, bpr, bpz, bpn, kb + 4, Aa, Ra, Za, Na);
    mfma_chunk4<GS>(acc, Ab, Rb, Zb, Nb);
  }
}

// ---------------- fused gates GEMM + GRU update ----------------
// grid 256 (1 block/CU): jt = b & 63 (XCD-pinned weight slice: XCD = b%8 = jt%8),
// rg2 = b >> 6 (64 batch rows = 4 m-tiles). 512 threads = 8 waves, 8-way k-split
// (12 kt each). Two-stage LDS reduce; GRU epilogue on waves 0-3.
// New-h fragments are written ONLY into A_next's h-part (pred reads them there).
__global__ __launch_bounds__(512, 2) void gates_fused(
    const unsigned short* __restrict__ A_sw, const unsigned short* __restrict__ Wg,
    const float* __restrict__ b_i, const float* __restrict__ b_hn,
    const float* __restrict__ h_in, float* __restrict__ h_out,
    unsigned short* __restrict__ A_next,
    const unsigned char* __restrict__ rb,
    float* __restrict__ r_out, int t) {
  int lane = threadIdx.x & 63, wave = threadIdx.x >> 6;
  int b = blockIdx.x;
  int jt = b & 63;
  int rg2 = b >> 6;   // 0..3

  __shared__ float4v red[4][4][2][64];   // 32 KB

  const short8* A8 = (const short8*)A_sw;
  const short8* B8 = (const short8*)Wg;

  float4v acc[4][4];
#pragma unroll
  for (int mi = 0; mi < 4; ++mi)
#pragma unroll
    for (int g = 0; g < 4; ++g) acc[mi][g] = (float4v){0.f, 0.f, 0.f, 0.f};

  const short8* ap0 = A8 + ((size_t)(rg2 * 4 + 0) * KTC) * 64 + lane;
  const short8* ap1 = A8 + ((size_t)(rg2 * 4 + 1) * KTC) * 64 + lane;
  const short8* ap2 = A8 + ((size_t)(rg2 * 4 + 2) * KTC) * 64 + lane;
  const short8* ap3 = A8 + ((size_t)(rg2 * 4 + 3) * KTC) * 64 + lane;
  const short8* bpr = B8 + ((size_t)(jt * 4 + 0) * KTC) * 64 + lane;
  const short8* bpz = B8 + ((size_t)(jt * 4 + 1) * KTC) * 64 + lane;
  const short8* bpi = B8 + ((size_t)(jt * 4 + 2) * KTC) * 64 + lane;
  const short8* bph = B8 + ((size_t)(jt * 4 + 3) * KTC) * 64 + lane;

  int k0 = wave * 12, k1 = k0 + 12;
  int e_end = (k1 < 64) ? k1 : 64;   // e segment end
  int h_st  = (k0 > 64) ? k0 : 64;   // h segment start

  gates_seg4<2>(acc, ap0, ap1, ap2, ap3, bpr, bpz, bpi, k0, e_end);  // e: r,z,n_i
  gates_seg4<3>(acc, ap0, ap1, ap2, ap3, bpr, bpz, bph, h_st, k1);   // h: r,z,n_h

  // stage 1: waves 4-7 -> waves 0-3 (g split in halves to fit 32 KB)
#pragma unroll
  for (int hh = 0; hh < 2; ++hh) {
    if (wave >= 4) {
#pragma unroll
      for (int mi = 0; mi < 4; ++mi) {
        red[wave - 4][mi][0][lane] = acc[mi][2 * hh];
        red[wave - 4][mi][1][lane] = acc[mi][2 * hh + 1];
      }
    }
    __syncthreads();
    if (wave < 4) {
#pragma unroll
      for (int mi = 0; mi < 4; ++mi) {
        acc[mi][2 * hh]     += red[wave][mi][0][lane];
        acc[mi][2 * hh + 1] += red[wave][mi][1][lane];
      }
    }
    __syncthreads();
  }
  // stage 2: all-to-all among waves 0-3; wave w owns m-tile w
  float4v accs[4];
#pragma unroll
  for (int hh = 0; hh < 2; ++hh) {
    if (wave < 4) {
#pragma unroll
      for (int mi = 0; mi < 4; ++mi) {
        red[wave][mi][0][lane] = acc[mi][2 * hh];
        red[wave][mi][1][lane] = acc[mi][2 * hh + 1];
      }
    }
    __syncthreads();
    if (wave < 4) {
      float4v s0 = red[0][wave][0][lane];
      float4v s1 = red[0][wave][1][lane];
#pragma unroll
      for (int w = 1; w < 4; ++w) {
        s0 += red[w][wave][0][lane];
        s1 += red[w][wave][1][lane];
      }
      accs[2 * hh] = s0; accs[2 * hh + 1] = s1;
    }
    __syncthreads();
  }

  // GRU epilogue (waves 0-3, 16 rows x 16 cols each)
  if (wave < 4) {
    int cl = lane & 15, q = lane >> 4;
    int jcol = (jt << 4) + cl;
    float br_ = b_i[jcol], bz_ = b_i[1024 + jcol], bn_ = b_i[2048 + jcol];
    float bh = b_hn[jcol];
    int row_base = rg2 * 64 + wave * 16 + q * 4;
#pragma unroll
    for (int rr = 0; rr < 4; ++rr) {
      int row = row_base + rr;
      float r = sigm(accs[0][rr] + br_);
      float z = sigm(accs[1][rr] + bz_);
      float n = tanhf(accs[2][rr] + bn_ + r * (accs[3][rr] + bh));
      float hv = h_in[(size_t)row * H_DIM + jcol];
      float nh = (1.f - z) * n + z * hv;
      r_out[((size_t)t * B_DIM + row) * H_DIM + jcol] = nh;
      if (t < T_DIM - 1) {
        int rst = rb[(t + 1) * B_DIM + row];
        float hm = rst ? 0.f : nh;
        h_out[(size_t)row * H_DIM + jcol] = hm;
        A_next[afrag(row, 2048 + jcol, KTC)] = f2bf(hm);  // pred + next gates read this
      }
    }
  }
}

// ---------------- fused pred GEMM + e_t / err for step t+1 ----------------
// grid 256: ntq = b&15 (64-col strip), mt = b>>4 (16 rows). 512 threads = 8 waves,
// k-split 4 kt each, full prefetch, h-fragments read directly from A_next's
// h-part (written by the gates dispatch that just finished). After an 8-wave LDS
// reduce, wave w (w<4) owns nt = ntq*4+w.
__global__ __launch_bounds__(512, 2) void pred_fused(
    const unsigned short* __restrict__ A_next, const unsigned short* __restrict__ Wp,
    const float* __restrict__ b_p, const float* __restrict__ a_all,
    const unsigned char* __restrict__ rb,
    unsigned short* __restrict__ A_next_w, float* __restrict__ err_out, int t) {
  int lane = threadIdx.x & 63, wave = threadIdx.x >> 6;
  int b = blockIdx.x;
  int ntq = b & 15, mt = b >> 4;

  const short8* A8 = (const short8*)A_next;
  const short8* B8 = (const short8*)Wp;

  // h-part of A row-tile mt: kt' = 64 + k/32 within stride-KTC layout
  const short8* hap = A8 + ((size_t)mt * KTC + 64) * 64 + lane;
  const short8* bp0 = B8 + ((size_t)(ntq * 4 + 0) * KTP) * 64 + lane;
  const short8* bp1 = B8 + ((size_t)(ntq * 4 + 1) * KTP) * 64 + lane;
  const short8* bp2 = B8 + ((size_t)(ntq * 4 + 2) * KTP) * 64 + lane;
  const short8* bp3 = B8 + ((size_t)(ntq * 4 + 3) * KTP) * 64 + lane;

  float4v acc[4];
#pragma unroll
  for (int n = 0; n < 4; ++n) acc[n] = (float4v){0.f, 0.f, 0.f, 0.f};

  {
    int pk0 = wave * 4;   // 8 waves x 4 kt = 32 kt
    short8 Aa[4], B0a[4], B1a[4], B2a[4], B3a[4];
    // A (h-fragments) first: IC-class latency
#pragma unroll
    for (int kk = 0; kk < 4; ++kk) Aa[kk] = hap[(size_t)(pk0 + kk) * 64];
#pragma unroll
    for (int kk = 0; kk < 4; ++kk) {
      size_t o = (size_t)(pk0 + kk) * 64;
      B0a[kk] = bp0[o]; B1a[kk] = bp1[o]; B2a[kk] = bp2[o]; B3a[kk] = bp3[o];
    }
#pragma unroll
    for (int kk = 0; kk < 4; ++kk) {
      acc[0] = __builtin_amdgcn_mfma_f32_16x16x32_bf16(Aa[kk], B0a[kk], acc[0], 0, 0, 0);
      acc[1] = __builtin_amdgcn_mfma_f32_16x16x32_bf16(Aa[kk], B1a[kk], acc[1], 0, 0, 0);
      acc[2] = __builtin_amdgcn_mfma_f32_16x16x32_bf16(Aa[kk], B2a[kk], acc[2], 0, 0, 0);
      acc[3] = __builtin_amdgcn_mfma_f32_16x16x32_bf16(Aa[kk], B3a[kk], acc[3], 0, 0, 0);
    }
  }

  __shared__ float4v red[8][4][64];        // 32 KB
  __shared__ float rsum_red[4][4][4];
#pragma unroll
  for (int n = 0; n < 4; ++n) red[wave][n][lane] = acc[n];
  __syncthreads();

  int cl = lane & 15, q = lane >> 4;

  if (wave < 4) {
    float4v s = red[0][wave][lane];
#pragma unroll
    for (int w = 1; w < 8; ++w) s += red[w][wave][lane];

    int coln = (ntq * 4 + wave) * 16 + cl;
    float bp = b_p[coln];
    float rsum[4];
#pragma unroll
    for (int rr = 0; rr < 4; ++rr) {
      int row = mt * 16 + q * 4 + rr;
      float ah = fmaxf(s[rr] + bp, 0.f);
      int rst = rb[(t + 1) * B_DIM + row];
      float am = rst ? 0.f : ah;
      float av = a_all[((size_t)(t + 1) * B_DIM + row) * H_DIM + coln];
      float d = av - am;
      float pos = fmaxf(d, 0.f), neg = fmaxf(-d, 0.f);
      A_next_w[afrag(row, coln, KTC)] = f2bf(pos);
      A_next_w[afrag(row, 1024 + coln, KTC)] = f2bf(neg);
      rsum[rr] = pos + neg;
    }
#pragma unroll
    for (int rr = 0; rr < 4; ++rr) {
      float sv = rsum[rr];
      sv += __shfl_xor(sv, 1);
      sv += __shfl_xor(sv, 2);
      sv += __shfl_xor(sv, 4);
      sv += __shfl_xor(sv, 8);
      if (cl == 0) rsum_red[wave][q][rr] = sv;
    }
  }
  __syncthreads();
  if (wave == 0 && lane < 16) {
    int qq = lane >> 2, rr = lane & 3;
    float sv = rsum_red[0][qq][rr] + rsum_red[1][qq][rr]
             + rsum_red[2][qq][rr] + rsum_red[3][qq][rr];
    int row = mt * 16 + qq * 4 + rr;
    atomicAdd(err_out + (size_t)(t + 1) * B_DIM + row, sv * (1.0f / (float)H_DIM));
  }
}

// ---------------- launch ----------------
extern "C" void kernel_launch(void* const* d_in, const int* in_sizes, int n_in,
                              void* d_out, int out_size, void* d_ws, size_t ws_size,
                              hipStream_t stream) {
  (void)in_sizes; (void)n_in; (void)out_size; (void)ws_size;
  const float* a_all = (const float*)d_in[0];
  const void*  resets = d_in[1];
  const float* W_i  = (const float*)d_in[2];
  const float* b_i  = (const float*)d_in[3];
  const float* W_h  = (const float*)d_in[4];
  const float* b_hn = (const float*)d_in[5];
  const float* W_p  = (const float*)d_in[6];
  const float* b_p  = (const float*)d_in[7];

  float* r_out = (float*)d_out;
  float* err_out = r_out + (size_t)T_DIM * B_DIM * H_DIM;

  char* ws = (char*)d_ws;
  unsigned short* Wg_sw = (unsigned short*)ws; ws += (size_t)256 * 16 * KC * 2;     // 25.2 MB
  unsigned short* Wp_sw = (unsigned short*)ws; ws += (size_t)H_DIM * H_DIM * 2;     // 2 MB
  unsigned short* A0    = (unsigned short*)ws; ws += (size_t)B_DIM * KC * 2;        // 1.5 MB
  unsigned short* A1    = (unsigned short*)ws; ws += (size_t)B_DIM * KC * 2;        // 1.5 MB
  float* h0 = (float*)ws; ws += (size_t)B_DIM * H_DIM * 4;                          // 1 MB
  float* h1 = (float*)ws; ws += (size_t)B_DIM * H_DIM * 4;                          // 1 MB
  unsigned char* rb = (unsigned char*)ws; ws += T_DIM * B_DIM;                      // 32 KB
  int* rflag = (int*)ws; ws += 256;

  hipMemsetAsync(err_out, 0, (size_t)T_DIM * B_DIM * sizeof(float), stream);
  detect_resets<<<1, 256, 0, stream>>>((const int*)resets, rflag);
  decode_resets<<<T_DIM, 256, 0, stream>>>(resets, rflag, rb);
  convert_gates<<<dim3(256, KTC), 256, 0, stream>>>(W_i, W_h, Wg_sw);
  convert_wp<<<dim3(H_DIM / 16, KTP), 256, 0, stream>>>(W_p, Wp_sw);
  init_state<<<B_DIM, 256, 0, stream>>>(a_all, A0, h0, err_out);

  for (int t = 0; t < T_DIM; ++t) {
    const unsigned short* Acur = (t & 1) ? A1 : A0;
    unsigned short* Anext      = (t & 1) ? A0 : A1;
    const float* hcur = (t & 1) ? h1 : h0;
    float* hnext      = (t & 1) ? h0 : h1;
    gates_fused<<<256, 512, 0, stream>>>(
        Acur, Wg_sw, b_i, b_hn, hcur, hnext, Anext, rb, r_out, t);
    if (t < T_DIM - 1)
      pred_fused<<<256, 512, 0, stream>>>(
          Anext, Wp_sw, b_p, a_all, rb, Anext, err_out, t);
  }
}